// Round 11
// baseline (363.913 us; speedup 1.0000x reference)
//
#include <hip/hip_runtime.h>
#include <hip/hip_bf16.h>

#define NN 20000
#define EE 320000
#define GG 256

__device__ __forceinline__ float lanebc(float v, int l){
  return __uint_as_float(__builtin_amdgcn_readlane(__float_as_uint(v), (unsigned)l));
}
__device__ __forceinline__ int lanebci(int v, int l){
  return __builtin_amdgcn_readlane(v, (unsigned)l);
}
__device__ __forceinline__ float wave_sum(float v){
  #pragma unroll
  for(int m=32;m>0;m>>=1) v += __shfl_xor(v, m, 64);
  return v;
}
__device__ __forceinline__ float elu(float o){
  return (o > 0.f) ? o : (__expf(o) - 1.f);
}
// softmax exp without max-pass: shift-invariant, clamp prevents overflow (scores are O(5))
__device__ __forceinline__ float pexp(float e){ return __expf(fminf(e, 60.f)); }
// bf16 pack/unpack
__device__ __forceinline__ float bf2f(ushort u){ return __uint_as_float((unsigned)u << 16); }
__device__ __forceinline__ ushort f2bf(float f){
  unsigned x = __float_as_uint(f);
  return (ushort)((x + 0x7FFFu + ((x >> 16) & 1u)) >> 16);
}

// ---------------- weights prep (one launch) ----------------
// blocks 0-47: float4-by-4k packs for the dense GEMMs
// block 48: head-packed folded edge weights for layer1 (Wf1p4[j*64+c] = {Wf1[j][hd*64+c]}_hd)
// block 49: folded edge weights for layer2 (raw layout)
__global__ void k_weights(const float* __restrict__ We9, const float* __restrict__ be,
                          const float* __restrict__ We1, const float* __restrict__ We2,
                          const float* __restrict__ att1,
                          const float* __restrict__ Wl1, const float* __restrict__ Wl2,
                          const float* __restrict__ Wr2,
                          float4* __restrict__ Wf1p4, float4* __restrict__ bf1p4,
                          float4* __restrict__ att1p4,
                          float* __restrict__ Wf2, float* __restrict__ bf2,
                          float4* __restrict__ Wl1p4, float4* __restrict__ Wl2p4,
                          float4* __restrict__ Wr2p4){
  const int b = blockIdx.x;
  const int tid = threadIdx.x;
  if (b < 48){
    const int idx = (b%16)*256 + tid;
    const int seg = b/16;
    if (seg == 0){
      const int k4 = idx>>8, c = idx&255;
      Wl1p4[idx] = make_float4(Wl1[(4*k4+0)*256+c], Wl1[(4*k4+1)*256+c],
                               Wl1[(4*k4+2)*256+c], Wl1[(4*k4+3)*256+c]);
    } else if (seg == 1){
      const int k4 = idx>>6, cc = idx&63;
      Wl2p4[idx] = make_float4(Wl2[(4*k4+0)*64+cc], Wl2[(4*k4+1)*64+cc],
                               Wl2[(4*k4+2)*64+cc], Wl2[(4*k4+3)*64+cc]);
    } else {
      const int k4 = idx>>6, cc = idx&63;
      Wr2p4[idx] = make_float4(Wr2[(4*k4+0)*64+cc], Wr2[(4*k4+1)*64+cc],
                               Wr2[(4*k4+2)*64+cc], Wr2[(4*k4+3)*64+cc]);
    }
  } else if (b == 48){
    if (tid < 64){
      const int c = tid;
      #pragma unroll
      for (int j=0;j<9;j++){
        float a0=0,a1=0,a2=0,a3=0;
        #pragma unroll
        for (int k=0;k<32;k++){
          const float w = We9[j*32+k];
          a0 += w*We1[k*256 +       c];
          a1 += w*We1[k*256 +  64 + c];
          a2 += w*We1[k*256 + 128 + c];
          a3 += w*We1[k*256 + 192 + c];
        }
        Wf1p4[j*64+c] = make_float4(a0,a1,a2,a3);
      }
      float b0=0,b1=0,b2=0,b3=0;
      #pragma unroll
      for (int k=0;k<32;k++){
        const float w = be[k];
        b0 += w*We1[k*256 +       c];
        b1 += w*We1[k*256 +  64 + c];
        b2 += w*We1[k*256 + 128 + c];
        b3 += w*We1[k*256 + 192 + c];
      }
      bf1p4[c] = make_float4(b0,b1,b2,b3);
      att1p4[c] = make_float4(att1[c], att1[64+c], att1[128+c], att1[192+c]);
    }
  } else {
    if (tid < 64){
      const int c = tid;
      #pragma unroll
      for (int j=0;j<9;j++){
        float a = 0.f;
        #pragma unroll
        for (int k=0;k<32;k++) a += We9[j*32+k]*We2[k*64+c];
        Wf2[j*64+c] = a;
      }
      float bb = 0.f;
      #pragma unroll
      for (int k=0;k<32;k++) bb += be[k]*We2[k*64+c];
      bf2[c] = bb;
    }
  }
}

// ---------------- in-degree count ----------------
__global__ void k_cnt(const int* __restrict__ ei, int* __restrict__ cnt){
  int e = blockIdx.x*256 + threadIdx.x;
  if (e < EE) atomicAdd(&cnt[ei[EE+e]], 1);
}

__global__ void k_alloc(const int* __restrict__ cnt, int* __restrict__ start, int* __restrict__ counter){
  int i = blockIdx.x*blockDim.x + threadIdx.x;
  if (i < NN) start[i] = atomicAdd(counter, cnt[i]);
}

// ---------------- scatter: build CSR-ordered srcp + edge-attr copy eap ----------------
__global__ void k_scatter(const int* __restrict__ ei, const float* __restrict__ ea,
                          const int* __restrict__ start, int* __restrict__ fill,
                          int* __restrict__ srcp, float* __restrict__ eap){
  int e = blockIdx.x*blockDim.x + threadIdx.x;
  if (e >= EE) return;
  int t = ei[EE + e];
  int p = start[t] + atomicAdd(&fill[t], 1);
  srcp[p] = ei[e];
  #pragma unroll
  for (int j=0;j<9;j++) eap[(size_t)p*9 + j] = ea[(size_t)e*9 + j];
}

// ---------------- fused node-MLP + layer-1 transform ----------------
// emits h0b[node][64] bf16; xlp/xrp[node][c*4+hd] head-packed bf16 (coalesced stores via col remap)
__global__ __launch_bounds__(256) void k_xlxr1f(
    const float* __restrict__ x, const float* __restrict__ Wcat,
    const float* __restrict__ bcat, const float* __restrict__ Wini,
    const float* __restrict__ bini, const float* __restrict__ Wl,
    const float* __restrict__ bl, const float* __restrict__ Wr,
    const float* __restrict__ br, ushort* __restrict__ h0b,
    ushort* __restrict__ xlp, ushort* __restrict__ xrp)
{
  const int n0 = blockIdx.x*8;
  const int tid = threadIdx.x;
  __shared__ float xs[8][25];
  __shared__ float sv[8][33];
  __shared__ __align__(16) float hsT[64][8];
  if (tid < 192){ int n=tid/24, j=tid%24; xs[n][j] = x[(size_t)(n0+n)*24 + j]; }
  __syncthreads();
  {
    const int n = tid>>5, cc = tid&31;
    float a = bcat[cc];
    #pragma unroll
    for (int k=0;k<16;k++) a += xs[n][k]*Wcat[k*32+cc];
    sv[n][cc] = fmaxf(a, 0.f);
  }
  __syncthreads();
  #pragma unroll
  for (int i=tid;i<512;i+=256){
    const int n = i>>6, c = i&63;
    float a = bini[c];
    #pragma unroll
    for (int k=0;k<8;k++)  a += xs[n][16+k]*Wini[k*64+c];
    #pragma unroll
    for (int k=0;k<32;k++) a += sv[n][k]*Wini[(8+k)*64+c];
    const float r = fmaxf(a, 0.f);
    hsT[c][n] = r;
    h0b[(size_t)(n0+n)*64 + c] = f2bf(r);
  }
  __syncthreads();
  // GEMM column col = hd*64+cc with hd=tid&3, cc=tid>>2 -> packed store index == tid (coalesced)
  const int col = (tid&3)*64 + (tid>>2);
  float accl[8], accr[8];
  const float blv = bl[col], brv = br[col];
  #pragma unroll
  for(int n=0;n<8;n++){ accl[n]=blv; accr[n]=brv; }
  for(int k=0;k<64;k++){
    const float wl = Wl[k*256 + col];
    const float wr = Wr[k*256 + col];
    const float4 ha = *(const float4*)&hsT[k][0];
    const float4 hb = *(const float4*)&hsT[k][4];
    accl[0]+=ha.x*wl; accr[0]+=ha.x*wr; accl[1]+=ha.y*wl; accr[1]+=ha.y*wr;
    accl[2]+=ha.z*wl; accr[2]+=ha.z*wr; accl[3]+=ha.w*wl; accr[3]+=ha.w*wr;
    accl[4]+=hb.x*wl; accr[4]+=hb.x*wr; accl[5]+=hb.y*wl; accr[5]+=hb.y*wr;
    accl[6]+=hb.z*wl; accr[6]+=hb.z*wr; accl[7]+=hb.w*wl; accr[7]+=hb.w*wr;
  }
  #pragma unroll
  for(int n=0;n<8;n++){
    xlp[(size_t)(n0+n)*256 + tid] = f2bf(accl[n]);
    xrp[(size_t)(n0+n)*256 + tid] = f2bf(accr[n]);
  }
}

// ---------------- layer-1 fused GATv2: score + softmax + h-space aggregate -> zb[N,4,64] ----------------
__global__ __launch_bounds__(256) void k_gat1(
    const int* __restrict__ cnt, const int* __restrict__ start,
    const int* __restrict__ srcp, const float* __restrict__ eap,
    const ushort* __restrict__ h0b, const ushort* __restrict__ xlp,
    const ushort* __restrict__ xrp,
    const float4* __restrict__ Wf1p4, const float4* __restrict__ bf1p4,
    const float4* __restrict__ att1p4, float* __restrict__ zb)
{
  const int t = blockIdx.x*4 + (threadIdx.x>>6);
  const int c = threadIdx.x & 63;
  const int st = start[t], dg = cnt[t];

  float4 wf[9];
  #pragma unroll
  for (int j=0;j<9;j++) wf[j] = Wf1p4[j*64 + c];
  const float4 attq = att1p4[c];
  const float4 bfq  = bf1p4[c];

  const ushort4 xr4 = *(const ushort4*)&xrp[(size_t)t*256 + c*4];
  const float xrt0=bf2f(xr4.x), xrt1=bf2f(xr4.y), xrt2=bf2f(xr4.z), xrt3=bf2f(xr4.w);
  const float h0t = bf2f(h0b[(size_t)t*64 + c]);

  int sL = 0;
  if (c < dg) sL = srcp[st + c];

  float den0=0,den1=0,den2=0,den3=0, z0=0,z1=0,z2=0,z3=0;
  float laS = 0.f;   // lanes 0-8 accumulate sum of incoming ea (for self-loop mean)

  const int d1 = min(dg, 64);
  for (int i=0;i<d1;i++){
    const int s = lanebci(sL, i);
    const float eav = (c<9)? eap[(size_t)(st+i)*9 + c] : 0.f;
    laS += eav;
    const ushort4 x4 = *(const ushort4*)&xlp[(size_t)s*256 + c*4];
    const float hv = bf2f(h0b[(size_t)s*64 + c]);
    float e0=bfq.x, e1=bfq.y, e2=bfq.z, e3=bfq.w;
    #pragma unroll
    for (int j=0;j<9;j++){
      const float la = lanebc(eav, j);
      e0 += la*wf[j].x; e1 += la*wf[j].y; e2 += la*wf[j].z; e3 += la*wf[j].w;
    }
    float m0 = bf2f(x4.x)+xrt0+e0, m1 = bf2f(x4.y)+xrt1+e1;
    float m2 = bf2f(x4.z)+xrt2+e2, m3 = bf2f(x4.w)+xrt3+e3;
    m0 = (m0>=0.f)?m0:0.2f*m0; m1 = (m1>=0.f)?m1:0.2f*m1;
    m2 = (m2>=0.f)?m2:0.2f*m2; m3 = (m3>=0.f)?m3:0.2f*m3;
    float s0 = attq.x*m0, s1 = attq.y*m1, s2 = attq.z*m2, s3 = attq.w*m3;
    #pragma unroll
    for (int mk=32;mk>0;mk>>=1){
      s0 += __shfl_xor(s0,mk,64); s1 += __shfl_xor(s1,mk,64);
      s2 += __shfl_xor(s2,mk,64); s3 += __shfl_xor(s3,mk,64);
    }
    const float p0=pexp(s0), p1=pexp(s1), p2=pexp(s2), p3=pexp(s3);
    den0+=p0; den1+=p1; den2+=p2; den3+=p3;
    z0+=p0*hv; z1+=p1*hv; z2+=p2*hv; z3+=p3*hv;
  }
  for (int i=64;i<dg;i++){
    const int s = srcp[st+i];
    const float eav = (c<9)? eap[(size_t)(st+i)*9 + c] : 0.f;
    laS += eav;
    const ushort4 x4 = *(const ushort4*)&xlp[(size_t)s*256 + c*4];
    const float hv = bf2f(h0b[(size_t)s*64 + c]);
    float e0=bfq.x, e1=bfq.y, e2=bfq.z, e3=bfq.w;
    #pragma unroll
    for (int j=0;j<9;j++){
      const float la = lanebc(eav, j);
      e0 += la*wf[j].x; e1 += la*wf[j].y; e2 += la*wf[j].z; e3 += la*wf[j].w;
    }
    float m0 = bf2f(x4.x)+xrt0+e0, m1 = bf2f(x4.y)+xrt1+e1;
    float m2 = bf2f(x4.z)+xrt2+e2, m3 = bf2f(x4.w)+xrt3+e3;
    m0 = (m0>=0.f)?m0:0.2f*m0; m1 = (m1>=0.f)?m1:0.2f*m1;
    m2 = (m2>=0.f)?m2:0.2f*m2; m3 = (m3>=0.f)?m3:0.2f*m3;
    float s0 = attq.x*m0, s1 = attq.y*m1, s2 = attq.z*m2, s3 = attq.w*m3;
    #pragma unroll
    for (int mk=32;mk>0;mk>>=1){
      s0 += __shfl_xor(s0,mk,64); s1 += __shfl_xor(s1,mk,64);
      s2 += __shfl_xor(s2,mk,64); s3 += __shfl_xor(s3,mk,64);
    }
    const float p0=pexp(s0), p1=pexp(s1), p2=pexp(s2), p3=pexp(s3);
    den0+=p0; den1+=p1; den2+=p2; den3+=p3;
    z0+=p0*hv; z1+=p1*hv; z2+=p2*hv; z3+=p3*hv;
  }
  // self-loop (mean edge attr; dg==0 -> ep = 0)
  float e0=0.f, e1=0.f, e2=0.f, e3=0.f;
  if (dg > 0){
    const float invc = 1.f/(float)dg;
    e0=bfq.x; e1=bfq.y; e2=bfq.z; e3=bfq.w;
    #pragma unroll
    for (int j=0;j<9;j++){
      const float la = lanebc(laS, j)*invc;
      e0 += la*wf[j].x; e1 += la*wf[j].y; e2 += la*wf[j].z; e3 += la*wf[j].w;
    }
  }
  const ushort4 xl4 = *(const ushort4*)&xlp[(size_t)t*256 + c*4];
  float m0 = bf2f(xl4.x)+xrt0+e0, m1 = bf2f(xl4.y)+xrt1+e1;
  float m2 = bf2f(xl4.z)+xrt2+e2, m3 = bf2f(xl4.w)+xrt3+e3;
  m0 = (m0>=0.f)?m0:0.2f*m0; m1 = (m1>=0.f)?m1:0.2f*m1;
  m2 = (m2>=0.f)?m2:0.2f*m2; m3 = (m3>=0.f)?m3:0.2f*m3;
  float s0 = attq.x*m0, s1 = attq.y*m1, s2 = attq.z*m2, s3 = attq.w*m3;
  #pragma unroll
  for (int mk=32;mk>0;mk>>=1){
    s0 += __shfl_xor(s0,mk,64); s1 += __shfl_xor(s1,mk,64);
    s2 += __shfl_xor(s2,mk,64); s3 += __shfl_xor(s3,mk,64);
  }
  const float p0=pexp(s0), p1=pexp(s1), p2=pexp(s2), p3=pexp(s3);
  den0+=p0; den1+=p1; den2+=p2; den3+=p3;
  z0+=p0*h0t; z1+=p1*h0t; z2+=p2*h0t; z3+=p3*h0t;

  zb[(size_t)t*256 +       c] = z0/(den0+1e-16f);
  zb[(size_t)t*256 +  64 + c] = z1/(den1+1e-16f);
  zb[(size_t)t*256 + 128 + c] = z2/(den2+1e-16f);
  zb[(size_t)t*256 + 192 + c] = z3/(den3+1e-16f);
}

// ---------------- fused register-blocked: h1 in LDS; xl2/xr2 = h1@{Wl2,Wr2} ----------------
__global__ __launch_bounds__(256) void k_h1xlxr2(
    const float* __restrict__ zb, const float4* __restrict__ Wl1p4,
    const float* __restrict__ bl1, const float* __restrict__ bias1,
    const float4* __restrict__ Wl2p4, const float* __restrict__ bl2,
    const float4* __restrict__ Wr2p4, const float* __restrict__ br2,
    ushort* __restrict__ xl2, ushort* __restrict__ xr2)
{
  const int n0 = blockIdx.x*16;
  const int tid = threadIdx.x;
  __shared__ float zT[256*20];
  __shared__ __align__(16) float4 hs[64][17];
  #pragma unroll
  for (int j=0;j<16;j++) zT[tid*20 + j] = zb[(size_t)(n0+j)*256 + tid];
  __syncthreads();
  {
    const int c = tid, hd = c>>6;
    float acc[16];
    const float b = bl1[c] + bias1[c];
    #pragma unroll
    for (int n=0;n<16;n++) acc[n]=b;
    #pragma unroll 4
    for (int k4=0;k4<16;k4++){
      const float4 w4 = Wl1p4[k4*256 + c];
      #pragma unroll
      for (int kk=0;kk<4;kk++){
        const float wk = (kk==0)?w4.x:(kk==1)?w4.y:(kk==2)?w4.z:w4.w;
        const float* zr = &zT[(hd*64 + k4*4 + kk)*20];
        const float4 z0 = *(const float4*)&zr[0];
        const float4 z1 = *(const float4*)&zr[4];
        const float4 z2 = *(const float4*)&zr[8];
        const float4 z3 = *(const float4*)&zr[12];
        acc[0]+=z0.x*wk; acc[1]+=z0.y*wk; acc[2]+=z0.z*wk; acc[3]+=z0.w*wk;
        acc[4]+=z1.x*wk; acc[5]+=z1.y*wk; acc[6]+=z1.z*wk; acc[7]+=z1.w*wk;
        acc[8]+=z2.x*wk; acc[9]+=z2.y*wk; acc[10]+=z2.z*wk; acc[11]+=z2.w*wk;
        acc[12]+=z3.x*wk; acc[13]+=z3.y*wk; acc[14]+=z3.z*wk; acc[15]+=z3.w*wk;
      }
    }
    float* hsf = (float*)hs;
    const int base = (c>>2)*17*4 + (c&3);
    #pragma unroll
    for (int n=0;n<16;n++) hsf[base + n*4] = elu(acc[n]);
  }
  __syncthreads();
  {
    const int cc = tid & 63, ng = tid >> 6;
    float al[4], ar[4];
    const float bl = bl2[cc], br = br2[cc];
    #pragma unroll
    for (int j=0;j<4;j++){ al[j]=bl; ar[j]=br; }
    #pragma unroll 4
    for (int k4=0;k4<64;k4++){
      const float4 wl = Wl2p4[k4*64 + cc];
      const float4 wr = Wr2p4[k4*64 + cc];
      #pragma unroll
      for (int j=0;j<4;j++){
        const float4 hv = hs[k4][ng*4 + j];
        al[j] += hv.x*wl.x + hv.y*wl.y + hv.z*wl.z + hv.w*wl.w;
        ar[j] += hv.x*wr.x + hv.y*wr.y + hv.z*wr.z + hv.w*wr.w;
      }
    }
    #pragma unroll
    for (int j=0;j<4;j++){
      xl2[(size_t)(n0+ng*4+j)*64 + cc] = f2bf(al[j]);
      xr2[(size_t)(n0+ng*4+j)*64 + cc] = f2bf(ar[j]);
    }
  }
}

// ---------------- layer-2 fused GATv2: score + softmax + aggregate + graph-pool ----------------
__global__ __launch_bounds__(256) void k_gat2(
    const int* __restrict__ cnt, const int* __restrict__ start,
    const int* __restrict__ srcp, const float* __restrict__ eap,
    const ushort* __restrict__ xl, const ushort* __restrict__ xr,
    const float* __restrict__ Wf2, const float* __restrict__ bf2,
    const float* __restrict__ att2, const float* __restrict__ bias2,
    const int* __restrict__ batch, float* __restrict__ pooled, int* __restrict__ gcnt)
{
  const int t = blockIdx.x*4 + (threadIdx.x>>6);
  const int c = threadIdx.x & 63;
  const int st = start[t], dg = cnt[t];

  float wf[9];
  #pragma unroll
  for (int j=0;j<9;j++) wf[j] = Wf2[j*64 + c];
  const float bfv = bf2[c], attv = att2[c];
  const float xrt = bf2f(xr[(size_t)t*64 + c]);
  const float xlt = bf2f(xl[(size_t)t*64 + c]);

  int sL = 0;
  if (c < dg) sL = srcp[st + c];

  float den=0.f, z=0.f, laS=0.f;
  const int d1 = min(dg, 64);
  for (int i=0;i<d1;i++){
    const int s = lanebci(sL, i);
    const float eav = (c<9)? eap[(size_t)(st+i)*9 + c] : 0.f;
    laS += eav;
    const float xlv = bf2f(xl[(size_t)s*64 + c]);
    float e0 = bfv;
    #pragma unroll
    for (int j=0;j<9;j++) e0 += lanebc(eav, j)*wf[j];
    float m = xlv + xrt + e0;
    m = (m>=0.f)? m : 0.2f*m;
    const float p = pexp(wave_sum(attv*m));
    den += p; z += p*xlv;
  }
  for (int i=64;i<dg;i++){
    const int s = srcp[st+i];
    const float eav = (c<9)? eap[(size_t)(st+i)*9 + c] : 0.f;
    laS += eav;
    const float xlv = bf2f(xl[(size_t)s*64 + c]);
    float e0 = bfv;
    #pragma unroll
    for (int j=0;j<9;j++) e0 += lanebc(eav, j)*wf[j];
    float m = xlv + xrt + e0;
    m = (m>=0.f)? m : 0.2f*m;
    const float p = pexp(wave_sum(attv*m));
    den += p; z += p*xlv;
  }
  // self-loop
  float e0 = 0.f;
  if (dg > 0){
    const float invc = 1.f/(float)dg;
    e0 = bfv;
    #pragma unroll
    for (int j=0;j<9;j++) e0 += lanebc(laS, j)*invc*wf[j];
  }
  float m = xlt + xrt + e0;
  m = (m>=0.f)? m : 0.2f*m;
  const float pS = pexp(wave_sum(attv*m));
  den += pS; z += pS*xlt;

  const float o = z/(den + 1e-16f) + bias2[c];
  const float r = elu(o);
  const int g = batch[t];
  atomicAdd(&pooled[g*64 + c], r);
  if (c == 0) atomicAdd(&gcnt[g], 1);
}

__global__ void k_out(const float* __restrict__ pooled, const int* __restrict__ gcnt,
                      const float* __restrict__ Wout, const float* __restrict__ bout,
                      float* __restrict__ out){
  int g = blockIdx.x, o = threadIdx.x;   // 128
  float a = 0.f;
  for(int k=0;k<64;k++) a += pooled[g*64 + k] * Wout[k*128 + o];
  float inv = 1.f / fmaxf((float)gcnt[g], 1.f);
  out[g*128 + o] = a*inv + bout[o];
}

extern "C" void kernel_launch(void* const* d_in, const int* in_sizes, int n_in,
                              void* d_out, int out_size, void* d_ws, size_t ws_size,
                              hipStream_t stream) {
  const float* x    = (const float*)d_in[0];
  const int*   ei   = (const int*)  d_in[1];
  const float* ea   = (const float*)d_in[2];
  const int*   batch= (const int*)  d_in[3];
  const float* Wcat = (const float*)d_in[4];
  const float* bcat = (const float*)d_in[5];
  const float* We   = (const float*)d_in[6];
  const float* be   = (const float*)d_in[7];
  const float* Wini = (const float*)d_in[8];
  const float* bini = (const float*)d_in[9];
  const float* Wl1  = (const float*)d_in[10];
  const float* bl1  = (const float*)d_in[11];
  const float* Wr1  = (const float*)d_in[12];
  const float* br1  = (const float*)d_in[13];
  const float* We1  = (const float*)d_in[14];
  const float* att1 = (const float*)d_in[15];
  const float* bias1= (const float*)d_in[16];
  const float* Wl2  = (const float*)d_in[17];
  const float* bl2  = (const float*)d_in[18];
  const float* Wr2  = (const float*)d_in[19];
  const float* br2  = (const float*)d_in[20];
  const float* We2  = (const float*)d_in[21];
  const float* att2 = (const float*)d_in[22];
  const float* bias2= (const float*)d_in[23];
  const float* Wout = (const float*)d_in[24];
  const float* bout = (const float*)d_in[25];
  float* out = (float*)d_out;
  char* ws = (char*)d_ws;

  size_t off = 0;
  auto alloc = [&](size_t bytes)->char*{ char* p = ws + off; off += (bytes + 255) & ~(size_t)255; return p; };
  ushort* h0b   = (ushort*)alloc((size_t)NN*64*2);
  ushort* xlp   = (ushort*)alloc((size_t)NN*256*2);
  ushort* xrp   = (ushort*)alloc((size_t)NN*256*2);
  float*  zb    = (float*) alloc((size_t)NN*256*4);
  ushort* xl2   = (ushort*)alloc((size_t)NN*64*2);
  ushort* xr2   = (ushort*)alloc((size_t)NN*64*2);
  float*  eap   = (float*) alloc((size_t)EE*9*4);
  float4* Wf1p4 = (float4*)alloc((size_t)9*64*16);
  float4* bf1p4 = (float4*)alloc((size_t)64*16);
  float4* att1p4= (float4*)alloc((size_t)64*16);
  float*  Wf2   = (float*) alloc((size_t)9*64*4);
  float*  bf2   = (float*) alloc((size_t)64*4);
  float4* Wl1p4 = (float4*)alloc((size_t)4096*16);
  float4* Wl2p4 = (float4*)alloc((size_t)4096*16);
  float4* Wr2p4 = (float4*)alloc((size_t)4096*16);
  int*    start = (int*)   alloc((size_t)NN*4);
  int*    srcp  = (int*)   alloc((size_t)EE*4);
  // ---- contiguous zero region ----
  const size_t zoff = off;
  int*    cnt   = (int*)   alloc((size_t)NN*4);
  int*    fill  = (int*)   alloc((size_t)NN*4);
  int*    counter = (int*) alloc(256);
  float*  pooled  = (float*)alloc((size_t)GG*64*4);
  int*    gcnt    = (int*)  alloc((size_t)GG*4);
  const size_t zlen = off - zoff;

  hipMemsetAsync(ws + zoff, 0, zlen, stream);

  k_weights <<<50, 256, 0, stream>>>(We, be, We1, We2, att1, Wl1, Wl2, Wr2,
                                     Wf1p4, bf1p4, att1p4, Wf2, bf2,
                                     Wl1p4, Wl2p4, Wr2p4);
  k_cnt     <<<(EE+255)/256, 256, 0, stream>>>(ei, cnt);
  k_alloc   <<<(NN+255)/256, 256, 0, stream>>>(cnt, start, counter);
  k_scatter <<<(EE+255)/256, 256, 0, stream>>>(ei, ea, start, fill, srcp, eap);
  k_xlxr1f  <<<NN/8, 256, 0, stream>>>(x, Wcat, bcat, Wini, bini,
                                       Wl1, bl1, Wr1, br1, h0b, xlp, xrp);
  k_gat1    <<<NN/4, 256, 0, stream>>>(cnt, start, srcp, eap, h0b, xlp, xrp,
                                       Wf1p4, bf1p4, att1p4, zb);
  k_h1xlxr2 <<<NN/16, 256, 0, stream>>>(zb, Wl1p4, bl1, bias1, Wl2p4, bl2, Wr2p4, br2, xl2, xr2);
  k_gat2    <<<NN/4, 256, 0, stream>>>(cnt, start, srcp, eap, xl2, xr2,
                                       Wf2, bf2, att2, bias2, batch, pooled, gcnt);
  k_out     <<<GG, 128, 0, stream>>>(pooled, gcnt, Wout, bout, out);
}